// Round 9
// baseline (358.116 us; speedup 1.0000x reference)
//
#include <hip/hip_runtime.h>
#include <cstdint>
#include <cstddef>

#define FDIM 1024   // feature dim F
#define DDIM 128    // fc out dim D
#define NGRAPH 64   // num graphs B
#define FCH 8       // feature chunks (XCD-local gather)
#define QN 4        // node quarters per graph

#define AS1 __attribute__((address_space(1)))
#define AS3 __attribute__((address_space(3)))

typedef float f32x4 __attribute__((ext_vector_type(4)));
typedef short s16x8 __attribute__((ext_vector_type(8)));

__device__ __forceinline__ unsigned short f2bf(float f) {
  unsigned int x = __float_as_uint(f);
  unsigned int r = (x + 0x7fffu + ((x >> 16) & 1u)) >> 16;  // RNE
  return (unsigned short)r;
}
__device__ __forceinline__ float bf2f(unsigned short u) {
  return __uint_as_float(((unsigned int)u) << 16);
}
__device__ __forceinline__ float bflo(unsigned int v) {
  return __uint_as_float(v << 16);
}
__device__ __forceinline__ float bfhi(unsigned int v) {
  return __uint_as_float(v & 0xffff0000u);
}

// ---------------------------------------------------------------------------
// init + cnt
// ---------------------------------------------------------------------------
__device__ __forceinline__ int lower_bound(const int* a, int n, int v) {
  int lo = 0, hi = n;
  while (lo < hi) {
    int mid = (lo + hi) >> 1;
    if (a[mid] < v) lo = mid + 1; else hi = mid;
  }
  return lo;
}
__global__ __launch_bounds__(256) void k_init_cnt(float4* pool1, float4* pool2,
                                                  int* deg1, int* deg2,
                                                  const int* __restrict__ batch1,
                                                  const int* __restrict__ batch2,
                                                  int* cnt1, int* gstart1,
                                                  int* cnt2, int* gstart2, int N) {
  int bid = blockIdx.x, t = threadIdx.x;
  const float4 z = make_float4(0.f, 0.f, 0.f, 0.f);
  if (bid < 64) {
    pool1[bid * 256 + t] = z;
  } else if (bid < 128) {
    pool2[(bid - 64) * 256 + t] = z;
  } else if (bid < 168) {
    int i = (bid - 128) * 256 + t;
    if (i < N) deg1[i] = 1;
  } else if (bid < 208) {
    int i = (bid - 168) * 256 + t;
    if (i < N) deg2[i] = 1;
  } else {
    if (t < 128) {
      const int* batch = (t < NGRAPH) ? batch1 : batch2;
      int* cnt = (t < NGRAPH) ? cnt1 : cnt2;
      int* gstart = (t < NGRAPH) ? gstart1 : gstart2;
      int g = t & (NGRAPH - 1);
      int lo = lower_bound(batch, N, g);
      int hi = lower_bound(batch, N, g + 1);
      gstart[g] = lo;
      cnt[g] = hi - lo;
    }
  }
}

// ---------------------------------------------------------------------------
// prep (merged branches): in-degree count. blockIdx.y = branch.
// ---------------------------------------------------------------------------
__global__ void k_prep(const int* __restrict__ ei1, const int* __restrict__ ei2,
                       int* deg1, int* deg2, int E) {
  const int* ei = blockIdx.y ? ei2 : ei1;
  int* deg = blockIdx.y ? deg2 : deg1;
  int i = blockIdx.x * blockDim.x + threadIdx.x;
  if (i < E) atomicAdd(&deg[ei[E + i]], 1);
}

// ---------------------------------------------------------------------------
// scan (merged): blockIdx.x = branch.
// ---------------------------------------------------------------------------
#define SCAN_T 1024
#define SCAN_PER 16
__global__ __launch_bounds__(SCAN_T) void k_scan(const int* __restrict__ deg1,
                                                 const int* __restrict__ deg2,
                                                 int* off1, int* off2,
                                                 int* cur1, int* cur2,
                                                 float* dinv1, float* dinv2, int n) {
  const int* deg = blockIdx.x ? deg2 : deg1;
  int* off = blockIdx.x ? off2 : off1;
  int* cur = blockIdx.x ? cur2 : cur1;
  float* dinv = blockIdx.x ? dinv2 : dinv1;
  __shared__ int sums[SCAN_T];
  int t = threadIdx.x;
  int base = t * SCAN_PER;
  int local[SCAN_PER];
  int s = 0;
  #pragma unroll
  for (int i = 0; i < SCAN_PER; ++i) {
    int idx = base + i;
    int d = (idx < n) ? deg[idx] : 0;
    local[i] = s;
    s += d;
    if (idx < n) dinv[idx] = rsqrtf((float)d);
  }
  sums[t] = s;
  __syncthreads();
  for (int o = 1; o < SCAN_T; o <<= 1) {
    int v = (t >= o) ? sums[t - o] : 0;
    __syncthreads();
    sums[t] += v;
    __syncthreads();
  }
  int basesum = (t > 0) ? sums[t - 1] : 0;
  #pragma unroll
  for (int i = 0; i < SCAN_PER; ++i) {
    int idx = base + i;
    if (idx < n) { int o = basesum + local[i]; off[idx] = o; cur[idx] = o; }
  }
  if (t == SCAN_T - 1) off[n] = sums[SCAN_T - 1];
}

// ---------------------------------------------------------------------------
// fill (merged): scatter edges + self-loops into CSR. blockIdx.y = branch.
// ---------------------------------------------------------------------------
__global__ void k_fill(const int* __restrict__ ei1, const int* __restrict__ ei2,
                       int* cur1, int* cur2,
                       const float* __restrict__ dinv1, const float* __restrict__ dinv2,
                       int* adjsrc1, int* adjsrc2,
                       float* adjw1, float* adjw2, int E, int N) {
  const int* ei = blockIdx.y ? ei2 : ei1;
  int* cur = blockIdx.y ? cur2 : cur1;
  const float* dinv = blockIdx.y ? dinv2 : dinv1;
  int* adjsrc = blockIdx.y ? adjsrc2 : adjsrc1;
  float* adjw = blockIdx.y ? adjw2 : adjw1;
  int i = blockIdx.x * blockDim.x + threadIdx.x;
  if (i < E) {
    int s = ei[i];
    int d = ei[E + i];
    int p = atomicAdd(&cur[d], 1);
    adjsrc[p] = s;
    adjw[p] = dinv[s] * dinv[d];
  }
  if (i < N) {
    int p = atomicAdd(&cur[i], 1);
    adjsrc[p] = i;
    adjw[p] = dinv[i] * dinv[i];
  }
}

// ---------------------------------------------------------------------------
// cast (merged): x1/x2 fp32->bf16; W1/W2 cast+transpose (64x64 LDS tiles).
// ---------------------------------------------------------------------------
__global__ __launch_bounds__(256) void k_cast(const float4* __restrict__ x1,
                                              const float4* __restrict__ x2,
                                              const float* __restrict__ W1,
                                              const float* __restrict__ W2,
                                              ushort4* xb1, ushort4* xb2,
                                              unsigned short* Wt1, unsigned short* Wt2,
                                              int n4, int nxb) {
  __shared__ unsigned short tile[64][65];
  int bid = blockIdx.x, t = threadIdx.x;
  if (bid < 2 * nxb) {
    int br = bid >= nxb;
    const float4* x = br ? x2 : x1;
    ushort4* xb = br ? xb2 : xb1;
    int i = (bid - br * nxb) * 256 + t;
    if (i < n4) {
      float4 v = x[i];
      ushort4 o;
      o.x = f2bf(v.x); o.y = f2bf(v.y); o.z = f2bf(v.z); o.w = f2bf(v.w);
      xb[i] = o;
    }
  } else {
    int w = bid - 2 * nxb;
    int br = w >= 256;
    const float* W = br ? W2 : W1;
    unsigned short* Wt = br ? Wt2 : Wt1;
    int tid16 = w - br * 256;
    int kb = tid16 >> 4, nb = tid16 & 15;
    int tn = t & 63, tg = t >> 6;
    #pragma unroll
    for (int r = 0; r < 16; ++r) {
      int kk = tg * 16 + r;
      tile[kk][tn] = f2bf(W[(size_t)(kb * 64 + kk) * FDIM + nb * 64 + tn]);
    }
    __syncthreads();
    #pragma unroll
    for (int r = 0; r < 16; ++r) {
      int nn = tg * 16 + r;
      Wt[(size_t)(nb * 64 + nn) * FDIM + kb * 64 + tn] = tile[tn][nn];
    }
  }
}

// ---------------------------------------------------------------------------
// GEMM bf16 MFMA v2b: 128x256 block tile, 4 waves 2x2, wave tile 64x128.
// BK=32, global_load_lds w16, XCD swizzle. Staging fully static per wave:
// wave w stages A-chunks {2w,2w+1} and B-chunks {4w..4w+3} (no branches).
// As 8 KB + Bs 16 KB = 24 KB LDS. acc[4][8].
// ---------------------------------------------------------------------------
__global__ __launch_bounds__(256, 2) void k_gemm_bf16(const unsigned short* __restrict__ A1,
                                                      const unsigned short* __restrict__ A2,
                                                      const unsigned short* __restrict__ B1,
                                                      const unsigned short* __restrict__ B2,
                                                      unsigned short* __restrict__ C1,
                                                      unsigned short* __restrict__ C2,
                                                      int M) {
  const unsigned short* A = blockIdx.y ? A2 : A1;
  const unsigned short* Bt = blockIdx.y ? B2 : B1;
  unsigned short* C = blockIdx.y ? C2 : C1;
  const int K = FDIM;
  __shared__ unsigned short sm[12288];  // As [0,4096) 128x32 ; Bs [4096,12288) 256x32
  int tid = threadIdx.x;
  int w = tid >> 6, lane = tid & 63;
  int wm = w >> 1, wn = w & 1;

  // XCD swizzle: grid.x = mt_pad * 4, divisible by 8
  int per_xcd = gridDim.x >> 3;
  int l = (blockIdx.x & 7) * per_xcd + (blockIdx.x >> 3);
  int m0 = (l >> 2) * 128;   // 4 n-tiles of 256
  int n0 = (l & 3) * 256;

  int sub = lane >> 2;   // row within 16-row chunk
  int kq = lane & 3;     // k-quarter (8 bf16)

  f32x4 acc[4][8];
  #pragma unroll
  for (int i = 0; i < 4; ++i)
    #pragma unroll
    for (int j = 0; j < 8; ++j)
      acc[i][j] = (f32x4){0.f, 0.f, 0.f, 0.f};

  for (int k0 = 0; k0 < K; k0 += 32) {
    // A: 8 chunks of 16 rows, 2 per wave (static assignment)
    #pragma unroll
    for (int j = 0; j < 2; ++j) {
      int chunk = w * 2 + j;
      int ra = m0 + chunk * 16 + sub;
      if (ra > M - 1) ra = M - 1;
      const unsigned short* ga = A + (size_t)ra * K + k0 + kq * 8;
      __builtin_amdgcn_global_load_lds((const AS1 unsigned int*)ga,
                                       (AS3 unsigned int*)&sm[chunk * 512], 16, 0, 0);
    }
    // B: 16 chunks of 16 rows, 4 per wave (static assignment)
    #pragma unroll
    for (int j = 0; j < 4; ++j) {
      int cb = w * 4 + j;
      int rb = n0 + cb * 16 + sub;
      const unsigned short* gb = Bt + (size_t)rb * K + k0 + kq * 8;
      __builtin_amdgcn_global_load_lds((const AS1 unsigned int*)gb,
                                       (AS3 unsigned int*)&sm[4096 + cb * 512], 16, 0, 0);
    }
    __syncthreads();
    s16x8 af[4], bfr[8];
    #pragma unroll
    for (int i = 0; i < 4; ++i) {
      int rowa = wm * 64 + i * 16 + (lane & 15);
      af[i] = *(const s16x8*)&sm[rowa * 32 + (lane >> 4) * 8];
    }
    #pragma unroll
    for (int j = 0; j < 8; ++j) {
      int rowb = wn * 128 + j * 16 + (lane & 15);
      bfr[j] = *(const s16x8*)&sm[4096 + rowb * 32 + (lane >> 4) * 8];
    }
    #pragma unroll
    for (int i = 0; i < 4; ++i)
      #pragma unroll
      for (int j = 0; j < 8; ++j)
        acc[i][j] = __builtin_amdgcn_mfma_f32_16x16x32_bf16(af[i], bfr[j], acc[i][j], 0, 0, 0);
    __syncthreads();
  }

  #pragma unroll
  for (int i = 0; i < 4; ++i) {
    int row_base = m0 + wm * 64 + i * 16 + (lane >> 4) * 4;
    #pragma unroll
    for (int j = 0; j < 8; ++j) {
      int col = n0 + wn * 128 + j * 16 + (lane & 15);
      #pragma unroll
      for (int r = 0; r < 4; ++r) {
        int row = row_base + r;
        if (row < M) C[(size_t)row * FDIM + col] = f2bf(acc[i][j][r]);
      }
    }
  }
}

// ---------------------------------------------------------------------------
// aggpool v3 (XCD-local + latency-hidden): unchanged from R6 (known-good).
// ---------------------------------------------------------------------------
__global__ __launch_bounds__(256) void k_aggpool(const unsigned short* __restrict__ h1,
                                                 const unsigned short* __restrict__ h2,
                                                 const int* __restrict__ off1,
                                                 const int* __restrict__ off2,
                                                 const int* __restrict__ adjsrc1,
                                                 const int* __restrict__ adjsrc2,
                                                 const float* __restrict__ adjw1,
                                                 const float* __restrict__ adjw2,
                                                 const float* __restrict__ bias1,
                                                 const float* __restrict__ bias2,
                                                 const int* __restrict__ cnt1,
                                                 const int* __restrict__ cnt2,
                                                 const int* __restrict__ gstart1,
                                                 const int* __restrict__ gstart2,
                                                 float* pool1, float* pool2) {
  int br = blockIdx.y;
  const unsigned short* h = br ? h2 : h1;
  const int* off = br ? off2 : off1;
  const int* adjsrc = br ? adjsrc2 : adjsrc1;
  const float* adjw = br ? adjw2 : adjw1;
  const float* bias = br ? bias2 : bias1;
  const int* cnt = br ? cnt2 : cnt1;
  const int* gstart = br ? gstart2 : gstart1;
  float* pool = br ? pool2 : pool1;

  int x = blockIdx.x;
  int chunk = x & (FCH - 1);
  int r = x >> 3;
  int g = r & (NGRAPH - 1);
  int q = r >> 6;

  int t = threadIdx.x;
  int grp = t >> 6, lane = t & 63;

  int n = cnt[g];
  int start = gstart[g];
  int per = (n + QN - 1) / QN;
  int v0 = start + q * per;
  int v1 = min(start + n, v0 + per);

  int colbase = chunk * 128 + lane * 2;
  const unsigned short* hc = h + colbase;
  float2 b2 = *(const float2*)(bias + colbase);
  float s0 = 0.f, s1 = 0.f;

  for (int v = v0 + grp; v < v1; v += 4) {
    int pb = off[v], pe = off[v + 1];
    float a0 = 0.f, a1 = 0.f;
    for (int pbb = pb; pbb < pe; pbb += 64) {
      int m = min(64, pe - pbb);
      int lp = pbb + ((lane < m) ? lane : (m - 1));
      int vs = adjsrc[lp];
      float vw = adjw[lp];
      int j = 0;
      for (; j + 4 <= m; j += 4) {
        int i0 = __shfl(vs, j),     i1 = __shfl(vs, j + 1);
        int i2 = __shfl(vs, j + 2), i3 = __shfl(vs, j + 3);
        float w0 = __shfl(vw, j),     w1 = __shfl(vw, j + 1);
        float w2 = __shfl(vw, j + 2), w3 = __shfl(vw, j + 3);
        unsigned int h0 = *(const unsigned int*)(hc + ((size_t)i0 << 10));
        unsigned int hv1 = *(const unsigned int*)(hc + ((size_t)i1 << 10));
        unsigned int hv2 = *(const unsigned int*)(hc + ((size_t)i2 << 10));
        unsigned int hv3 = *(const unsigned int*)(hc + ((size_t)i3 << 10));
        a0 += w0 * bflo(h0);  a1 += w0 * bfhi(h0);
        a0 += w1 * bflo(hv1); a1 += w1 * bfhi(hv1);
        a0 += w2 * bflo(hv2); a1 += w2 * bfhi(hv2);
        a0 += w3 * bflo(hv3); a1 += w3 * bfhi(hv3);
      }
      for (; j < m; ++j) {
        int i0 = __shfl(vs, j);
        float w0 = __shfl(vw, j);
        unsigned int h0 = *(const unsigned int*)(hc + ((size_t)i0 << 10));
        a0 += w0 * bflo(h0);
        a1 += w0 * bfhi(h0);
      }
    }
    a0 += b2.x; a1 += b2.y;
    s0 += (a0 >= 0.f) ? a0 : 0.01f * a0;
    s1 += (a1 >= 0.f) ? a1 : 0.01f * a1;
  }

  __shared__ float sm[4][128];
  sm[grp][lane * 2] = s0;
  sm[grp][lane * 2 + 1] = s1;
  __syncthreads();
  if (t < 128) {
    float sum = sm[0][t] + sm[1][t] + sm[2][t] + sm[3][t];
    float ic = 1.0f / fmaxf((float)n, 1.0f);
    atomicAdd(pool + (size_t)g * FDIM + chunk * 128 + t, sum * ic);
  }
}

// ---------------------------------------------------------------------------
// fc (merged): blockIdx.y = branch. out[64,128] = leaky(pool @ W + b)
// ---------------------------------------------------------------------------
__global__ __launch_bounds__(DDIM) void k_fc(const float* __restrict__ pool1,
                                             const float* __restrict__ pool2,
                                             const float* __restrict__ W1,
                                             const float* __restrict__ W2,
                                             const float* __restrict__ b1,
                                             const float* __restrict__ b2,
                                             float* out1, float* out2) {
  const float* pool = blockIdx.y ? pool2 : pool1;
  const float* W = blockIdx.y ? W2 : W1;
  const float* b = blockIdx.y ? b2 : b1;
  float* out = blockIdx.y ? out2 : out1;
  int g = blockIdx.x;
  int j = threadIdx.x;
  __shared__ float xs[FDIM];
  for (int k = j; k < FDIM; k += DDIM) xs[k] = pool[(size_t)g * FDIM + k];
  __syncthreads();
  float acc = b[j];
  for (int k = 0; k < FDIM; ++k) acc += xs[k] * W[(size_t)k * DDIM + j];
  out[g * DDIM + j] = (acc >= 0.f) ? acc : 0.01f * acc;
}

// ---------------------------------------------------------------------------
// final: out[g] = concat(o1,o2) @ finalW + finalb
// ---------------------------------------------------------------------------
__global__ __launch_bounds__(DDIM) void k_final(const float* __restrict__ o1,
                                                const float* __restrict__ o2,
                                                const float* __restrict__ W,
                                                const float* __restrict__ b,
                                                float* __restrict__ out) {
  int g = blockIdx.x;
  int t = threadIdx.x;
  float acc = o1[g * DDIM + t] * W[t] + o2[g * DDIM + t] * W[DDIM + t];
  #pragma unroll
  for (int o = 32; o > 0; o >>= 1) acc += __shfl_down(acc, o);
  __shared__ float ws2[2];
  if ((t & 63) == 0) ws2[t >> 6] = acc;
  __syncthreads();
  if (t == 0) out[g] = ws2[0] + ws2[1] + b[0];
}

// ---------------------------------------------------------------------------
extern "C" void kernel_launch(void* const* d_in, const int* in_sizes, int n_in,
                              void* d_out, int out_size, void* d_ws, size_t ws_size,
                              hipStream_t stream) {
  const float* x1 = (const float*)d_in[0];
  const int* ei1 = (const int*)d_in[1];
  const int* batch1 = (const int*)d_in[2];
  const float* x2 = (const float*)d_in[3];
  const int* ei2 = (const int*)d_in[4];
  const int* batch2 = (const int*)d_in[5];
  const float* conv1_W = (const float*)d_in[10];
  const float* conv1_b = (const float*)d_in[11];
  const float* fc1_W = (const float*)d_in[12];
  const float* fc1_b = (const float*)d_in[13];
  const float* conv2_W = (const float*)d_in[14];
  const float* conv2_b = (const float*)d_in[15];
  const float* fc2_W = (const float*)d_in[16];
  const float* fc2_b = (const float*)d_in[17];
  const float* final_W = (const float*)d_in[18];
  const float* final_b = (const float*)d_in[19];
  float* out = (float*)d_out;

  const int N = in_sizes[2];      // 10000
  const int E = in_sizes[1] / 2;  // 80000
  const int A = E + N;

  size_t off_b = 0;
  auto alloc = [&](size_t bytes) -> void* {
    void* p = (char*)d_ws + off_b;
    off_b += (bytes + 255) & ~(size_t)255;
    return p;
  };
  unsigned short* xbf1 = (unsigned short*)alloc((size_t)N * FDIM * 2);
  unsigned short* xbf2 = (unsigned short*)alloc((size_t)N * FDIM * 2);
  unsigned short* hbf1 = (unsigned short*)alloc((size_t)N * FDIM * 2);
  unsigned short* hbf2 = (unsigned short*)alloc((size_t)N * FDIM * 2);
  unsigned short* Wt1 = (unsigned short*)alloc((size_t)FDIM * FDIM * 2);
  unsigned short* Wt2 = (unsigned short*)alloc((size_t)FDIM * FDIM * 2);
  int* deg1 = (int*)alloc(N * 4);
  int* deg2 = (int*)alloc(N * 4);
  int* cnt1 = (int*)alloc(NGRAPH * 4);
  int* cnt2 = (int*)alloc(NGRAPH * 4);
  int* gstart1 = (int*)alloc(NGRAPH * 4);
  int* gstart2 = (int*)alloc(NGRAPH * 4);
  int* off1 = (int*)alloc((N + 1) * 4);
  int* off2 = (int*)alloc((N + 1) * 4);
  int* cur1 = (int*)alloc(N * 4);
  int* cur2 = (int*)alloc(N * 4);
  float* dinv1 = (float*)alloc(N * 4);
  float* dinv2 = (float*)alloc(N * 4);
  int* adjsrc1 = (int*)alloc((size_t)A * 4);
  int* adjsrc2 = (int*)alloc((size_t)A * 4);
  float* adjw1 = (float*)alloc((size_t)A * 4);
  float* adjw2 = (float*)alloc((size_t)A * 4);
  float* pool1 = (float*)alloc(NGRAPH * FDIM * 4);
  float* pool2 = (float*)alloc(NGRAPH * FDIM * 4);
  float* fco1 = (float*)alloc(NGRAPH * DDIM * 4);
  float* fco2 = (float*)alloc(NGRAPH * DDIM * 4);

  const int T = 256;
  int gE = (E + T - 1) / T;
  int n4 = N * FDIM / 4;
  int nxb = (n4 + T - 1) / T;
  int mt_pad = (N + 127) / 128;
  if (mt_pad & 1) mt_pad += 1;          // make grid.x = mt_pad*4 divisible by 8
  dim3 gGemm(mt_pad * 4, 2);
  dim3 gPrep(gE, 2);
  dim3 gAgg(FCH * NGRAPH * QN, 2);
  dim3 gFc(NGRAPH, 2);

  k_init_cnt<<<209, T, 0, stream>>>((float4*)pool1, (float4*)pool2, deg1, deg2,
                                    batch1, batch2, cnt1, gstart1, cnt2, gstart2, N);
  k_prep<<<gPrep, T, 0, stream>>>(ei1, ei2, deg1, deg2, E);
  k_scan<<<2, SCAN_T, 0, stream>>>(deg1, deg2, off1, off2, cur1, cur2, dinv1, dinv2, N);
  k_fill<<<gPrep, T, 0, stream>>>(ei1, ei2, cur1, cur2, dinv1, dinv2,
                                  adjsrc1, adjsrc2, adjw1, adjw2, E, N);
  k_cast<<<2 * nxb + 512, T, 0, stream>>>((const float4*)x1, (const float4*)x2,
                                          conv1_W, conv2_W,
                                          (ushort4*)xbf1, (ushort4*)xbf2, Wt1, Wt2,
                                          n4, nxb);
  k_gemm_bf16<<<gGemm, 256, 0, stream>>>(xbf1, xbf2, Wt1, Wt2, hbf1, hbf2, N);
  k_aggpool<<<gAgg, 256, 0, stream>>>(hbf1, hbf2, off1, off2, adjsrc1, adjsrc2,
                                      adjw1, adjw2, conv1_b, conv2_b,
                                      cnt1, cnt2, gstart1, gstart2, pool1, pool2);
  k_fc<<<gFc, DDIM, 0, stream>>>(pool1, pool2, fc1_W, fc2_W, fc1_b, fc2_b, fco1, fco2);
  k_final<<<NGRAPH, DDIM, 0, stream>>>(fco1, fco2, final_W, final_b, out);
}

// Round 11
// 333.073 us; speedup vs baseline: 1.0752x; 1.0752x over previous
//
#include <hip/hip_runtime.h>
#include <cstdint>
#include <cstddef>

#define FDIM 1024   // feature dim F
#define DDIM 128    // fc out dim D
#define NGRAPH 64   // num graphs B
#define FCH 8       // feature chunks (XCD-local gather)
#define QN 4        // node quarters per graph
#define FILLB 320   // fill-block range in k_fill_gemm (mult of 8)

#define AS1 __attribute__((address_space(1)))
#define AS3 __attribute__((address_space(3)))

typedef float f32x4 __attribute__((ext_vector_type(4)));
typedef short s16x8 __attribute__((ext_vector_type(8)));

__device__ __forceinline__ unsigned short f2bf(float f) {
  unsigned int x = __float_as_uint(f);
  unsigned int r = (x + 0x7fffu + ((x >> 16) & 1u)) >> 16;  // RNE
  return (unsigned short)r;
}
__device__ __forceinline__ float bflo(unsigned int v) {
  return __uint_as_float(v << 16);
}
__device__ __forceinline__ float bfhi(unsigned int v) {
  return __uint_as_float(v & 0xffff0000u);
}

// ---------------------------------------------------------------------------
// init: deg=1 (blocks 0..39 deg1, 40..79 deg2), block 80: cnt/gstart both.
// ---------------------------------------------------------------------------
__device__ __forceinline__ int lower_bound(const int* a, int n, int v) {
  int lo = 0, hi = n;
  while (lo < hi) {
    int mid = (lo + hi) >> 1;
    if (a[mid] < v) lo = mid + 1; else hi = mid;
  }
  return lo;
}
__global__ __launch_bounds__(256) void k_init(int* deg1, int* deg2,
                                              const int* __restrict__ batch1,
                                              const int* __restrict__ batch2,
                                              int* cnt1, int* gstart1,
                                              int* cnt2, int* gstart2, int N) {
  int bid = blockIdx.x, t = threadIdx.x;
  if (bid < 40) {
    int i = bid * 256 + t;
    if (i < N) deg1[i] = 1;
  } else if (bid < 80) {
    int i = (bid - 40) * 256 + t;
    if (i < N) deg2[i] = 1;
  } else {
    if (t < 128) {
      const int* batch = (t < NGRAPH) ? batch1 : batch2;
      int* cnt = (t < NGRAPH) ? cnt1 : cnt2;
      int* gstart = (t < NGRAPH) ? gstart1 : gstart2;
      int g = t & (NGRAPH - 1);
      int lo = lower_bound(batch, N, g);
      int hi = lower_bound(batch, N, g + 1);
      gstart[g] = lo;
      cnt[g] = hi - lo;
    }
  }
}

// ---------------------------------------------------------------------------
// prep+cast (merged, grid.y = branch):
//   x in [0, gE)            : in-degree atomics (latency-bound)
//   x in [gE, gE+nxb)       : x fp32 -> bf16 cast (BW-bound)
//   x in [gE+nxb, +256)     : W cast+transpose (64x64 LDS tiles)
// Latency-bound prep co-schedules with BW-bound cast -> prep time hidden.
// ---------------------------------------------------------------------------
__global__ __launch_bounds__(256) void k_prep_cast(const int* __restrict__ ei1,
                                                   const int* __restrict__ ei2,
                                                   int* deg1, int* deg2,
                                                   const float4* __restrict__ x1,
                                                   const float4* __restrict__ x2,
                                                   const float* __restrict__ W1,
                                                   const float* __restrict__ W2,
                                                   ushort4* xb1, ushort4* xb2,
                                                   unsigned short* Wt1, unsigned short* Wt2,
                                                   int E, int n4, int gE, int nxb) {
  __shared__ unsigned short tile[64][65];
  int br = blockIdx.y;
  int x = blockIdx.x, t = threadIdx.x;
  if (x < gE) {
    const int* ei = br ? ei2 : ei1;
    int* deg = br ? deg2 : deg1;
    int i = x * 256 + t;
    if (i < E) atomicAdd(&deg[ei[E + i]], 1);
  } else if (x < gE + nxb) {
    const float4* xx = br ? x2 : x1;
    ushort4* xb = br ? xb2 : xb1;
    int i = (x - gE) * 256 + t;
    if (i < n4) {
      float4 v = xx[i];
      ushort4 o;
      o.x = f2bf(v.x); o.y = f2bf(v.y); o.z = f2bf(v.z); o.w = f2bf(v.w);
      xb[i] = o;
    }
  } else {
    const float* W = br ? W2 : W1;
    unsigned short* Wt = br ? Wt2 : Wt1;
    int tid16 = x - gE - nxb;        // 0..255
    int kb = tid16 >> 4, nb = tid16 & 15;
    int tn = t & 63, tg = t >> 6;
    #pragma unroll
    for (int r = 0; r < 16; ++r) {
      int kk = tg * 16 + r;
      tile[kk][tn] = f2bf(W[(size_t)(kb * 64 + kk) * FDIM + nb * 64 + tn]);
    }
    __syncthreads();
    #pragma unroll
    for (int r = 0; r < 16; ++r) {
      int nn = tg * 16 + r;
      Wt[(size_t)(nb * 64 + nn) * FDIM + kb * 64 + tn] = tile[tn][nn];
    }
  }
}

// ---------------------------------------------------------------------------
// scan (merged): blockIdx.x = branch.
// ---------------------------------------------------------------------------
#define SCAN_T 1024
#define SCAN_PER 16
__global__ __launch_bounds__(SCAN_T) void k_scan(const int* __restrict__ deg1,
                                                 const int* __restrict__ deg2,
                                                 int* off1, int* off2,
                                                 int* cur1, int* cur2,
                                                 float* dinv1, float* dinv2, int n) {
  const int* deg = blockIdx.x ? deg2 : deg1;
  int* off = blockIdx.x ? off2 : off1;
  int* cur = blockIdx.x ? cur2 : cur1;
  float* dinv = blockIdx.x ? dinv2 : dinv1;
  __shared__ int sums[SCAN_T];
  int t = threadIdx.x;
  int base = t * SCAN_PER;
  int local[SCAN_PER];
  int s = 0;
  #pragma unroll
  for (int i = 0; i < SCAN_PER; ++i) {
    int idx = base + i;
    int d = (idx < n) ? deg[idx] : 0;
    local[i] = s;
    s += d;
    if (idx < n) dinv[idx] = rsqrtf((float)d);
  }
  sums[t] = s;
  __syncthreads();
  for (int o = 1; o < SCAN_T; o <<= 1) {
    int v = (t >= o) ? sums[t - o] : 0;
    __syncthreads();
    sums[t] += v;
    __syncthreads();
  }
  int basesum = (t > 0) ? sums[t - 1] : 0;
  #pragma unroll
  for (int i = 0; i < SCAN_PER; ++i) {
    int idx = base + i;
    if (idx < n) { int o = basesum + local[i]; off[idx] = o; cur[idx] = o; }
  }
  if (t == SCAN_T - 1) off[n] = sums[SCAN_T - 1];
}

// ---------------------------------------------------------------------------
// fill+gemm (merged, grid.y = branch):
//   x in [0, FILLB)  : CSR fill (latency-bound atomics; x<gE active)
//   x in [FILLB, +mt*8) : bf16 MFMA GEMM, 128x128 tile (R6 config), XCD swz.
// Fill is independent of GEMM inputs; its latency hides under GEMM.
// ---------------------------------------------------------------------------
__global__ __launch_bounds__(256) void k_fill_gemm(const int* __restrict__ ei1,
                                                   const int* __restrict__ ei2,
                                                   int* cur1, int* cur2,
                                                   const float* __restrict__ dinv1,
                                                   const float* __restrict__ dinv2,
                                                   int* adjsrc1, int* adjsrc2,
                                                   float* adjw1, float* adjw2,
                                                   const unsigned short* __restrict__ A1,
                                                   const unsigned short* __restrict__ A2,
                                                   const unsigned short* __restrict__ B1,
                                                   const unsigned short* __restrict__ B2,
                                                   unsigned short* __restrict__ C1,
                                                   unsigned short* __restrict__ C2,
                                                   int E, int N, int M) {
  __shared__ unsigned short sm[8192];  // gemm: As [0,4096) 128x32 ; Bs [4096,8192)
  int br = blockIdx.y;
  if (blockIdx.x < FILLB) {
    const int* ei = br ? ei2 : ei1;
    int* cur = br ? cur2 : cur1;
    const float* dinv = br ? dinv2 : dinv1;
    int* adjsrc = br ? adjsrc2 : adjsrc1;
    float* adjw = br ? adjw2 : adjw1;
    int i = blockIdx.x * 256 + threadIdx.x;
    if (i < E) {
      int s = ei[i];
      int d = ei[E + i];
      int p = atomicAdd(&cur[d], 1);
      adjsrc[p] = s;
      adjw[p] = dinv[s] * dinv[d];
    }
    if (i < N) {
      int p = atomicAdd(&cur[i], 1);
      adjsrc[p] = i;
      adjw[p] = dinv[i] * dinv[i];
    }
    return;
  }
  // ---- GEMM path (R6 128x128 config) ----
  const unsigned short* A = br ? A2 : A1;
  const unsigned short* Bt = br ? B2 : B1;
  unsigned short* C = br ? C2 : C1;
  const int K = FDIM;
  int tid = threadIdx.x;
  int w = tid >> 6, lane = tid & 63;
  int wm = w >> 1, wn = w & 1;

  int bx = blockIdx.x - FILLB;                 // 0 .. mt*8-1
  int per_xcd = (gridDim.x - FILLB) >> 3;
  int l = (bx & 7) * per_xcd + (bx >> 3);
  int m0 = (l >> 3) * 128;                     // nt == 8
  int n0 = (l & 7) * 128;

  int sub = lane >> 2;
  int kq = lane & 3;

  f32x4 acc[4][4];
  #pragma unroll
  for (int i = 0; i < 4; ++i)
    #pragma unroll
    for (int j = 0; j < 4; ++j)
      acc[i][j] = (f32x4){0.f, 0.f, 0.f, 0.f};

  for (int k0 = 0; k0 < K; k0 += 32) {
    #pragma unroll
    for (int j = 0; j < 2; ++j) {
      int chunk = w * 2 + j;
      int ra = m0 + chunk * 16 + sub;
      if (ra > M - 1) ra = M - 1;
      const unsigned short* ga = A + (size_t)ra * K + k0 + kq * 8;
      __builtin_amdgcn_global_load_lds((const AS1 unsigned int*)ga,
                                       (AS3 unsigned int*)&sm[chunk * 512], 16, 0, 0);
      int rb = n0 + chunk * 16 + sub;
      const unsigned short* gb = Bt + (size_t)rb * K + k0 + kq * 8;
      __builtin_amdgcn_global_load_lds((const AS1 unsigned int*)gb,
                                       (AS3 unsigned int*)&sm[4096 + chunk * 512], 16, 0, 0);
    }
    __syncthreads();
    s16x8 af[4], bfr[4];
    #pragma unroll
    for (int i = 0; i < 4; ++i) {
      int rowa = wm * 64 + i * 16 + (lane & 15);
      af[i] = *(const s16x8*)&sm[rowa * 32 + (lane >> 4) * 8];
      int rowb = wn * 64 + i * 16 + (lane & 15);
      bfr[i] = *(const s16x8*)&sm[4096 + rowb * 32 + (lane >> 4) * 8];
    }
    #pragma unroll
    for (int i = 0; i < 4; ++i)
      #pragma unroll
      for (int j = 0; j < 4; ++j)
        acc[i][j] = __builtin_amdgcn_mfma_f32_16x16x32_bf16(af[i], bfr[j], acc[i][j], 0, 0, 0);
    __syncthreads();
  }

  #pragma unroll
  for (int i = 0; i < 4; ++i) {
    int row_base = m0 + wm * 64 + i * 16 + (lane >> 4) * 4;
    #pragma unroll
    for (int j = 0; j < 4; ++j) {
      int col = n0 + wn * 64 + j * 16 + (lane & 15);
      #pragma unroll
      for (int r = 0; r < 4; ++r) {
        int row = row_base + r;
        if (row < M) C[(size_t)row * FDIM + col] = f2bf(acc[i][j][r]);
      }
    }
  }
}

// ---------------------------------------------------------------------------
// aggpool v4 (XCD-local, atomic-free): as R6 v3, but each (g,chunk,q) block
// writes its partial to pool4[q][g][f] with plain stores; fc sums partials.
// ---------------------------------------------------------------------------
__global__ __launch_bounds__(256) void k_aggpool(const unsigned short* __restrict__ h1,
                                                 const unsigned short* __restrict__ h2,
                                                 const int* __restrict__ off1,
                                                 const int* __restrict__ off2,
                                                 const int* __restrict__ adjsrc1,
                                                 const int* __restrict__ adjsrc2,
                                                 const float* __restrict__ adjw1,
                                                 const float* __restrict__ adjw2,
                                                 const float* __restrict__ bias1,
                                                 const float* __restrict__ bias2,
                                                 const int* __restrict__ cnt1,
                                                 const int* __restrict__ cnt2,
                                                 const int* __restrict__ gstart1,
                                                 const int* __restrict__ gstart2,
                                                 float* pool4_1, float* pool4_2) {
  int br = blockIdx.y;
  const unsigned short* h = br ? h2 : h1;
  const int* off = br ? off2 : off1;
  const int* adjsrc = br ? adjsrc2 : adjsrc1;
  const float* adjw = br ? adjw2 : adjw1;
  const float* bias = br ? bias2 : bias1;
  const int* cnt = br ? cnt2 : cnt1;
  const int* gstart = br ? gstart2 : gstart1;
  float* pool4 = br ? pool4_2 : pool4_1;

  int x = blockIdx.x;
  int chunk = x & (FCH - 1);
  int r = x >> 3;
  int g = r & (NGRAPH - 1);
  int q = r >> 6;

  int t = threadIdx.x;
  int grp = t >> 6, lane = t & 63;

  int n = cnt[g];
  int start = gstart[g];
  int per = (n + QN - 1) / QN;
  int v0 = start + q * per;
  int v1 = min(start + n, v0 + per);

  int colbase = chunk * 128 + lane * 2;
  const unsigned short* hc = h + colbase;
  float2 b2 = *(const float2*)(bias + colbase);
  float s0 = 0.f, s1 = 0.f;

  for (int v = v0 + grp; v < v1; v += 4) {
    int pb = off[v], pe = off[v + 1];
    float a0 = 0.f, a1 = 0.f;
    for (int pbb = pb; pbb < pe; pbb += 64) {
      int m = min(64, pe - pbb);
      int lp = pbb + ((lane < m) ? lane : (m - 1));
      int vs = adjsrc[lp];
      float vw = adjw[lp];
      int j = 0;
      for (; j + 4 <= m; j += 4) {
        int i0 = __shfl(vs, j),     i1 = __shfl(vs, j + 1);
        int i2 = __shfl(vs, j + 2), i3 = __shfl(vs, j + 3);
        float w0 = __shfl(vw, j),     w1 = __shfl(vw, j + 1);
        float w2 = __shfl(vw, j + 2), w3 = __shfl(vw, j + 3);
        unsigned int h0 = *(const unsigned int*)(hc + ((size_t)i0 << 10));
        unsigned int hv1 = *(const unsigned int*)(hc + ((size_t)i1 << 10));
        unsigned int hv2 = *(const unsigned int*)(hc + ((size_t)i2 << 10));
        unsigned int hv3 = *(const unsigned int*)(hc + ((size_t)i3 << 10));
        a0 += w0 * bflo(h0);  a1 += w0 * bfhi(h0);
        a0 += w1 * bflo(hv1); a1 += w1 * bfhi(hv1);
        a0 += w2 * bflo(hv2); a1 += w2 * bfhi(hv2);
        a0 += w3 * bflo(hv3); a1 += w3 * bfhi(hv3);
      }
      for (; j < m; ++j) {
        int i0 = __shfl(vs, j);
        float w0 = __shfl(vw, j);
        unsigned int h0 = *(const unsigned int*)(hc + ((size_t)i0 << 10));
        a0 += w0 * bflo(h0);
        a1 += w0 * bfhi(h0);
      }
    }
    a0 += b2.x; a1 += b2.y;
    s0 += (a0 >= 0.f) ? a0 : 0.01f * a0;
    s1 += (a1 >= 0.f) ? a1 : 0.01f * a1;
  }

  __shared__ float sm[4][128];
  sm[grp][lane * 2] = s0;
  sm[grp][lane * 2 + 1] = s1;
  __syncthreads();
  if (t < 128) {
    float sum = sm[0][t] + sm[1][t] + sm[2][t] + sm[3][t];
    float ic = 1.0f / fmaxf((float)n, 1.0f);
    pool4[((size_t)(q * NGRAPH + g)) * FDIM + chunk * 128 + t] = sum * ic;
  }
}

// ---------------------------------------------------------------------------
// fc (merged): blockIdx.y = branch. Sums the QN pool partials, then
// out[64,128] = leaky(pool @ W + b)
// ---------------------------------------------------------------------------
__global__ __launch_bounds__(DDIM) void k_fc(const float* __restrict__ pool4_1,
                                             const float* __restrict__ pool4_2,
                                             const float* __restrict__ W1,
                                             const float* __restrict__ W2,
                                             const float* __restrict__ b1,
                                             const float* __restrict__ b2,
                                             float* out1, float* out2) {
  const float* pool4 = blockIdx.y ? pool4_2 : pool4_1;
  const float* W = blockIdx.y ? W2 : W1;
  const float* b = blockIdx.y ? b2 : b1;
  float* out = blockIdx.y ? out2 : out1;
  int g = blockIdx.x;
  int j = threadIdx.x;
  __shared__ float xs[FDIM];
  for (int k = j; k < FDIM; k += DDIM) {
    float v = 0.f;
    #pragma unroll
    for (int q = 0; q < QN; ++q)
      v += pool4[((size_t)(q * NGRAPH + g)) * FDIM + k];
    xs[k] = v;
  }
  __syncthreads();
  float acc = b[j];
  for (int k = 0; k < FDIM; ++k) acc += xs[k] * W[(size_t)k * DDIM + j];
  out[g * DDIM + j] = (acc >= 0.f) ? acc : 0.01f * acc;
}

// ---------------------------------------------------------------------------
// final: out[g] = concat(o1,o2) @ finalW + finalb
// ---------------------------------------------------------------------------
__global__ __launch_bounds__(DDIM) void k_final(const float* __restrict__ o1,
                                                const float* __restrict__ o2,
                                                const float* __restrict__ W,
                                                const float* __restrict__ b,
                                                float* __restrict__ out) {
  int g = blockIdx.x;
  int t = threadIdx.x;
  float acc = o1[g * DDIM + t] * W[t] + o2[g * DDIM + t] * W[DDIM + t];
  #pragma unroll
  for (int o = 32; o > 0; o >>= 1) acc += __shfl_down(acc, o);
  __shared__ float ws2[2];
  if ((t & 63) == 0) ws2[t >> 6] = acc;
  __syncthreads();
  if (t == 0) out[g] = ws2[0] + ws2[1] + b[0];
}

// ---------------------------------------------------------------------------
extern "C" void kernel_launch(void* const* d_in, const int* in_sizes, int n_in,
                              void* d_out, int out_size, void* d_ws, size_t ws_size,
                              hipStream_t stream) {
  const float* x1 = (const float*)d_in[0];
  const int* ei1 = (const int*)d_in[1];
  const int* batch1 = (const int*)d_in[2];
  const float* x2 = (const float*)d_in[3];
  const int* ei2 = (const int*)d_in[4];
  const int* batch2 = (const int*)d_in[5];
  const float* conv1_W = (const float*)d_in[10];
  const float* conv1_b = (const float*)d_in[11];
  const float* fc1_W = (const float*)d_in[12];
  const float* fc1_b = (const float*)d_in[13];
  const float* conv2_W = (const float*)d_in[14];
  const float* conv2_b = (const float*)d_in[15];
  const float* fc2_W = (const float*)d_in[16];
  const float* fc2_b = (const float*)d_in[17];
  const float* final_W = (const float*)d_in[18];
  const float* final_b = (const float*)d_in[19];
  float* out = (float*)d_out;

  const int N = in_sizes[2];      // 10000
  const int E = in_sizes[1] / 2;  // 80000
  const int A = E + N;

  size_t off_b = 0;
  auto alloc = [&](size_t bytes) -> void* {
    void* p = (char*)d_ws + off_b;
    off_b += (bytes + 255) & ~(size_t)255;
    return p;
  };
  unsigned short* xbf1 = (unsigned short*)alloc((size_t)N * FDIM * 2);
  unsigned short* xbf2 = (unsigned short*)alloc((size_t)N * FDIM * 2);
  unsigned short* hbf1 = (unsigned short*)alloc((size_t)N * FDIM * 2);
  unsigned short* hbf2 = (unsigned short*)alloc((size_t)N * FDIM * 2);
  unsigned short* Wt1 = (unsigned short*)alloc((size_t)FDIM * FDIM * 2);
  unsigned short* Wt2 = (unsigned short*)alloc((size_t)FDIM * FDIM * 2);
  int* deg1 = (int*)alloc(N * 4);
  int* deg2 = (int*)alloc(N * 4);
  int* cnt1 = (int*)alloc(NGRAPH * 4);
  int* cnt2 = (int*)alloc(NGRAPH * 4);
  int* gstart1 = (int*)alloc(NGRAPH * 4);
  int* gstart2 = (int*)alloc(NGRAPH * 4);
  int* off1 = (int*)alloc((N + 1) * 4);
  int* off2 = (int*)alloc((N + 1) * 4);
  int* cur1 = (int*)alloc(N * 4);
  int* cur2 = (int*)alloc(N * 4);
  float* dinv1 = (float*)alloc(N * 4);
  float* dinv2 = (float*)alloc(N * 4);
  int* adjsrc1 = (int*)alloc((size_t)A * 4);
  int* adjsrc2 = (int*)alloc((size_t)A * 4);
  float* adjw1 = (float*)alloc((size_t)A * 4);
  float* adjw2 = (float*)alloc((size_t)A * 4);
  float* pool4_1 = (float*)alloc((size_t)QN * NGRAPH * FDIM * 4);
  float* pool4_2 = (float*)alloc((size_t)QN * NGRAPH * FDIM * 4);
  float* fco1 = (float*)alloc(NGRAPH * DDIM * 4);
  float* fco2 = (float*)alloc(NGRAPH * DDIM * 4);

  const int T = 256;
  int gE = (E + T - 1) / T;                 // 313
  int n4 = N * FDIM / 4;
  int nxb = (n4 + T - 1) / T;               // 10000
  int mt = (N + 127) / 128;                 // 79
  dim3 gPrepCast(gE + nxb + 256, 2);
  dim3 gFillGemm(FILLB + mt * 8, 2);        // 320 + 632 (both mult-of-8 ranges)
  dim3 gAgg(FCH * NGRAPH * QN, 2);
  dim3 gFc(NGRAPH, 2);

  k_init<<<81, T, 0, stream>>>(deg1, deg2, batch1, batch2,
                               cnt1, gstart1, cnt2, gstart2, N);
  k_prep_cast<<<gPrepCast, T, 0, stream>>>(ei1, ei2, deg1, deg2,
                                           (const float4*)x1, (const float4*)x2,
                                           conv1_W, conv2_W,
                                           (ushort4*)xbf1, (ushort4*)xbf2, Wt1, Wt2,
                                           E, n4, gE, nxb);
  k_scan<<<2, SCAN_T, 0, stream>>>(deg1, deg2, off1, off2, cur1, cur2, dinv1, dinv2, N);
  k_fill_gemm<<<gFillGemm, T, 0, stream>>>(ei1, ei2, cur1, cur2, dinv1, dinv2,
                                           adjsrc1, adjsrc2, adjw1, adjw2,
                                           xbf1, xbf2, Wt1, Wt2, hbf1, hbf2,
                                           E, N, N);
  k_aggpool<<<gAgg, T, 0, stream>>>(hbf1, hbf2, off1, off2, adjsrc1, adjsrc2,
                                    adjw1, adjw2, conv1_b, conv2_b,
                                    cnt1, cnt2, gstart1, gstart2, pool4_1, pool4_2);
  k_fc<<<gFc, DDIM, 0, stream>>>(pool4_1, pool4_2, fc1_W, fc2_W, fc1_b, fc2_b, fco1, fco2);
  k_final<<<NGRAPH, DDIM, 0, stream>>>(fco1, fco2, final_W, final_b, out);
}